// Round 10
// baseline (120.792 us; speedup 1.0000x reference)
//
#include <hip/hip_runtime.h>
#include <hip/hip_bf16.h>

#define NBASIS 10
#define CDIM 16
#define DKDIM 8
#define JDIM 16

typedef _Float16 half8 __attribute__((ext_vector_type(8)));
typedef float floatx4 __attribute__((ext_vector_type(4)));

// adaptive load: f32 flag (wave-uniform) selects fp32 or bf16 interpretation
__device__ __forceinline__ float ldf(const void* p, int i, int f32) {
    if (f32) return ((const float*)p)[i];
    return __bfloat162float(((const __hip_bfloat16*)p)[i]);
}

// per-wave input-dtype detect (round-2 notes): fp32 data read as bf16 shows
// implausible magnitudes in ~half the ushorts; bf16 N(0,1) shows none.
__device__ __forceinline__ int detect_f32(const void* x) {
    unsigned short b = ((const unsigned short*)x)[threadIdx.x & 63];
    float v = __uint_as_float(((unsigned int)b) << 16);
    bool bad = !(fabsf(v) < 1000.0f) || (v != 0.0f && fabsf(v) < 1e-15f);
    unsigned long long m = __ballot(bad);
    return (__popcll(m) >= 8) ? 1 : 0;
}

__device__ __forceinline__ const float* uniform_ptr(const float* p) {
    uint64_t v = (uint64_t)p;
    uint32_t lo = __builtin_amdgcn_readfirstlane((uint32_t)v);
    uint32_t hi = __builtin_amdgcn_readfirstlane((uint32_t)(v >> 32));
    return (const float*)(((uint64_t)hi << 32) | lo);
}

// ---------------- prep: W1 fp32, B-matrix fp16 fragment-packed, q=x@Wq ------
// Bpk flat index = ((nt*8 + ks)*64 + lane)*8 + j  (one dwordx4 per lane/frag)
//   kk = ks*32 + (lane>>4)*8 + j  -> c = kk>>4, jj = kk&15   (K = (c,j) = 256)
//   nn = nt*16 + (lane&15)        -> net = nn>>7, m = (nn>>3)&15, o = nn&7
__global__ __launch_bounds__(256) void prep_kernel(
    const void* __restrict__ x, const void* __restrict__ Wq,
    const void* __restrict__ Wk1, const void* __restrict__ Wk2,
    const void* __restrict__ Wv1, const void* __restrict__ Wv2,
    float* __restrict__ w1k, float* __restrict__ w1v,
    float* __restrict__ qbuf, float* __restrict__ zbuf,
    float* __restrict__ outacc, _Float16* __restrict__ Bpk, int N)
{
    const int f32 = detect_f32(x);
    int i = blockIdx.x * 256 + threadIdx.x;
    if (i < 160) { w1k[i] = ldf(Wk1, i, f32); w1v[i] = ldf(Wv1, i, f32); }
    if (i < 65536) {
        int j = i & 7, lane = (i >> 3) & 63, ks = (i >> 9) & 7, nt = i >> 12;
        int kk = ks * 32 + (lane >> 4) * 8 + j;
        int nn = nt * 16 + (lane & 15);
        int c = kk >> 4, jj = kk & 15;
        int net = nn >> 7, m = (nn >> 3) & 15, o = nn & 7;
        float v = ldf(net ? Wv2 : Wk2, m * 2048 + c * 128 + jj * 8 + o, f32);
        Bpk[i] = (_Float16)v;
    }
    if (i < N) {
        zbuf[i] = 0.0f;
        float xr[CDIM];
        #pragma unroll
        for (int c = 0; c < CDIM; ++c) xr[c] = ldf(x, i * CDIM + c, f32);
        #pragma unroll
        for (int o = 0; o < DKDIM; ++o) {
            float acc = 0.0f;
            #pragma unroll
            for (int c = 0; c < CDIM; ++c)
                acc = fmaf(xr[c], ldf(Wq, c * DKDIM + o, f32), acc);
            qbuf[i * DKDIM + o] = acc;
        }
    }
    if (i < N * 8) outacc[i] = 0.0f;
}

// ---------------- edge kernel: geometry -> MFMA GEMM -> in-register epilogue
// block = 256 thr = 4 waves = 64 edges. ks-OUTER GEMM: per ks load 4 A frags
// (LDS, once) + 4 B frags (global), 16 MFMAs into acc[l][rt] (16 indep
// chains). h-contraction per lane (m = (2nt + col>>3)&15, o = col&7), then
// shfl_xor(8) merges m-halves. 4 barriers total.
__global__ __launch_bounds__(256) void edge_kernel(
    const void* __restrict__ pos, const void* __restrict__ x,
    const int* __restrict__ esrc, const int* __restrict__ edst,
    const float* __restrict__ w1k, const float* __restrict__ w1v,
    const float* __restrict__ qbuf, const _Float16* __restrict__ Bpk,
    float* __restrict__ zbuf, float* __restrict__ outacc, int E)
{
    __shared__ _Float16 A[16384];        // [rt][ks][lane][8] fp16 frags, 32 KB
    __shared__ union {
        struct { float xs[64][17]; float sh[64][17]; } g;     // geometry
        struct { float pk[2][64][9]; float pv[2][64][9]; } p; // partial k/v
    } u;
    __shared__ float hmf[2][16][68];     // [net][m][e], stride 68: conflict-
                                         // free writes + 16B-aligned reads
    __shared__ float cut_lds[64];
    __shared__ float evs_lds[64];
    __shared__ int   d_lds[64];

    const int f32  = detect_f32(x);
    const int tid  = threadIdx.x;
    const int lane = tid & 63;
    const int w    = tid >> 6;
    const int q    = lane >> 4;
    const int e0   = blockIdx.x * 64;
    const int e_g  = e0 + lane;
    const int eidx = (e_g < E) ? e_g : (E - 1);
    const int s = esrc[eidx], d = edst[eidx];

    // ---- geometry (per-edge work split across the 4 waves) ----
    float vx = ldf(pos, s * 3 + 0, f32) - ldf(pos, d * 3 + 0, f32);
    float vy = ldf(pos, s * 3 + 1, f32) - ldf(pos, d * 3 + 1, f32);
    float vz = ldf(pos, s * 3 + 2, f32) - ldf(pos, d * 3 + 2, f32);
    float r2 = vx * vx + vy * vy + vz * vz;
    float r  = sqrtf(r2 + 1e-18f);          // ref: emb/cutoff radius has +eps

    if (w == 0) {            // spherical harmonics + cutoff + dst
        float rsh = sqrtf(r2);              // ref: SH radius has no eps
        float inv = 1.0f / fmaxf(rsh, 1e-9f);
        float ux = vx * inv, uy = vy * inv, uz = vz * inv;
        const float s3   = 1.7320508075688772f;
        const float s5   = 2.23606797749979f;
        const float s15  = 3.872983346207417f;
        const float c358 = 2.091650066335189f;
        const float c218 = 1.6201851746019651f;
        const float s105 = 10.246950765959598f;
        const float s7h  = 1.3228756555322954f;
        float xx = ux * ux, yy = uy * uy, zz = uz * uz;
        float sh[16];
        sh[0] = 1.0f;
        sh[1] = s3 * ux; sh[2] = s3 * uy; sh[3] = s3 * uz;
        sh[4] = s15 * ux * uy;
        sh[5] = s15 * uy * uz;
        sh[6] = 0.5f * s5 * (3.0f * zz - 1.0f);
        sh[7] = s15 * ux * uz;
        sh[8] = 0.5f * s15 * (xx - yy);
        sh[9] = c358 * uy * (3.0f * xx - yy);
        sh[10] = s105 * ux * uy * uz;
        sh[11] = c218 * uy * (5.0f * zz - 1.0f);
        sh[12] = s7h * uz * (5.0f * zz - 3.0f);
        sh[13] = c218 * ux * (5.0f * zz - 1.0f);
        sh[14] = 0.5f * s105 * uz * (xx - yy);
        sh[15] = c358 * ux * (xx - 3.0f * yy);
        #pragma unroll
        for (int j = 0; j < 16; ++j) u.g.sh[lane][j] = sh[j];
        float tcut = 10.0f * (1.0f - r * (1.0f / 3.5f));
        cut_lds[lane] = (tcut > 0.0f) ? expf(-1.0f / tcut) : 0.0f;
        d_lds[lane] = d;
    } else if (w == 1) {     // xs gather
        #pragma unroll
        for (int c = 0; c < CDIM; ++c)
            u.g.xs[lane][c] = ldf(x, s * CDIM + c, f32);
    } else {                 // w=2: h_k, w=3: h_v -> hmf[net][m][e] (fp32)
        const float* w1 = uniform_ptr((w == 2) ? w1k : w1v);
        const int net = w - 2;
        float emb[NBASIS];
        const float step = 3.5f / 11.0f;
        const float istep = 11.0f / 3.5f;
        const float coef = (float)(1.14136 * 7.38905609893065 * 3.1622776601683795);
        #pragma unroll
        for (int i = 0; i < NBASIS; ++i) {
            float uu = (r - step * (float)(i + 1)) * istep; uu *= uu;
            emb[i] = (uu < 1.0f) ? coef * expf(-1.0f / (1.0f - uu)) : 0.0f;
        }
        const float inv_s10 = 0.31622776601683794f;
        #pragma unroll
        for (int m = 0; m < 16; ++m) {
            float pre = 0.0f;
            #pragma unroll
            for (int nb = 0; nb < NBASIS; ++nb)
                pre = fmaf(emb[nb], w1[nb * 16 + m], pre);
            pre *= inv_s10;
            hmf[net][m][lane] = pre / (1.0f + expf(-pre));   // silu
        }
    }
    __syncthreads();   // [1] geometry visible

    // ---- A-frag build (wave w -> row-tile rt=w), store to dedicated A ----
    {
        const int erow = w * 16 + (lane & 15);
        const int coff = q >> 1, jj0 = (q & 1) * 8;
        half8* Af = (half8*)A;
        #pragma unroll
        for (int ks = 0; ks < 8; ++ks) {
            float xsv = u.g.xs[erow][ks * 2 + coff];
            half8 a;
            #pragma unroll
            for (int j = 0; j < 8; ++j)
                a[j] = (_Float16)(xsv * u.g.sh[erow][jj0 + j]);
            Af[(w * 8 + ks) * 64 + lane] = a;
        }
    }
    __syncthreads();   // [2] A visible (and all geometry reads complete)

    // ---- GEMM, ks-outer: A once, B once, 16 indep MFMA chains ----
    floatx4 acc[4][4];   // [l][rt]
    #pragma unroll
    for (int l = 0; l < 4; ++l)
        #pragma unroll
        for (int rt = 0; rt < 4; ++rt) acc[l][rt] = (floatx4){0.f, 0.f, 0.f, 0.f};
    {
        const half8* Af = (const half8*)A;
        const half8* Bf = (const half8*)Bpk;
        #pragma unroll
        for (int ks = 0; ks < 8; ++ks) {
            half8 a[4], b[4];
            #pragma unroll
            for (int rt = 0; rt < 4; ++rt)
                a[rt] = Af[(rt * 8 + ks) * 64 + lane];
            #pragma unroll
            for (int l = 0; l < 4; ++l)
                b[l] = Bf[((4 * w + l) * 8 + ks) * 64 + lane];
            #pragma unroll
            for (int l = 0; l < 4; ++l)
                #pragma unroll
                for (int rt = 0; rt < 4; ++rt)
                    acc[l][rt] = __builtin_amdgcn_mfma_f32_16x16x32_f16(
                        a[rt], b[l], acc[l][rt], 0, 0, 0);
        }
    }

    // ---- h-contraction (m = (2nt + b3)&15) + m-half merge ----
    float part[16];      // [rt*4+rr]: partial k or v for edge rt*16+q*4+rr
    #pragma unroll
    for (int i = 0; i < 16; ++i) part[i] = 0.0f;
    const int b3  = (lane >> 3) & 1;
    const int net = w >> 1;             // 0 = k (nt 0-7), 1 = v (nt 8-15)
    #pragma unroll
    for (int l = 0; l < 4; ++l) {
        const int m = (2 * (4 * w + l) + b3) & 15;
        #pragma unroll
        for (int rt = 0; rt < 4; ++rt) {
            const float* hp = &hmf[net][m][rt * 16 + q * 4];
            #pragma unroll
            for (int rr = 0; rr < 4; ++rr)
                part[rt * 4 + rr] = fmaf(hp[rr], acc[l][rt][rr], part[rt * 4 + rr]);
        }
    }
    #pragma unroll
    for (int i = 0; i < 16; ++i) part[i] += __shfl_xor(part[i], 8, 64);

    // partial writes overlay geometry — all g reads finished before [2]
    if (b3 == 0) {
        const int o = lane & 7;
        #pragma unroll
        for (int i = 0; i < 16; ++i) {
            const int e = (i >> 2) * 16 + q * 4 + (i & 3);
            if (w < 2) u.p.pk[w][e][o] = part[i];
            else       u.p.pv[w - 2][e][o] = part[i];
        }
    }
    __syncthreads();   // [3] partials visible

    // ---- softmax: logit -> ev -> atomic z (one thread per edge) ----
    if (tid < 64) {
        const int dd = d_lds[tid];
        float logit = 0.0f;
        #pragma unroll
        for (int o = 0; o < 8; ++o) {
            float kv = u.p.pk[0][tid][o] + u.p.pk[1][tid][o];
            logit = fmaf(qbuf[(size_t)dd * 8 + o], kv, logit);
        }
        // scale: 1/64 (fcnet+norm) * 1/sqrt(8) (dk)
        logit *= (1.0f / 64.0f) * 0.35355339059327373f;
        float ev = cut_lds[tid] * expf(logit);   // unstabilized, matches ref
        if (e0 + tid < E) atomicAdd(&zbuf[dd], ev);
        evs_lds[tid] = sqrtf(ev);
    }
    __syncthreads();   // [4] ev visible

    // ---- out += sqrt(ev) * v (folded softmax; finalize divides by sqrt(z))
    {
        const int el = tid & 63, op = tid >> 6;
        if (e0 + el < E) {
            const int dd = d_lds[el];
            const float wq = evs_lds[el] * (1.0f / 64.0f);
            float v0 = u.p.pv[0][el][2 * op]     + u.p.pv[1][el][2 * op];
            float v1 = u.p.pv[0][el][2 * op + 1] + u.p.pv[1][el][2 * op + 1];
            atomicAdd(&outacc[(size_t)dd * 8 + 2 * op],     wq * v0);
            atomicAdd(&outacc[(size_t)dd * 8 + 2 * op + 1], wq * v1);
        }
    }
}

// ---------------- finalize: out = outacc / sqrt(z), dtype-adaptive ----------
__global__ __launch_bounds__(256) void finalize_kernel(
    const float* __restrict__ outacc, const float* __restrict__ zbuf,
    void* __restrict__ out, const void* __restrict__ x, int n)
{
    const int f32 = detect_f32(x);
    int i = blockIdx.x * 256 + threadIdx.x;
    if (i < n) {
        float z = zbuf[i >> 3];
        z = (z == 0.0f) ? 1.0f : z;
        float val = outacc[i] / sqrtf(z);
        if (f32) ((float*)out)[i] = val;
        else ((__hip_bfloat16*)out)[i] = __float2bfloat16(val);
    }
}

extern "C" void kernel_launch(void* const* d_in, const int* in_sizes, int n_in,
                              void* d_out, int out_size, void* d_ws, size_t ws_size,
                              hipStream_t stream)
{
    const void* pos = d_in[0];
    const void* x   = d_in[1];
    const void* Wq  = d_in[2];
    const void* Wk1 = d_in[3];
    const void* Wk2 = d_in[4];
    const void* Wv1 = d_in[5];
    const void* Wv2 = d_in[6];
    const int* esrc = (const int*)d_in[7];
    const int* edst = (const int*)d_in[8];
    const int N = in_sizes[1] / CDIM;
    const int E = in_sizes[7];

    float* ws = (float*)d_ws;
    float* w1k    = ws;                          // 160
    float* w1v    = w1k + 160;                   // 160
    float* qbuf   = w1v + 160;                   // N*8
    float* zbuf   = qbuf + (size_t)N * 8;        // N
    float* outacc = zbuf + N;                    // N*8
    _Float16* Bpk = (_Float16*)(outacc + (size_t)N * 8);  // 65536 fp16

    int prep_threads = N * 8 > 65536 ? N * 8 : 65536;
    int prep_blocks = (prep_threads + 255) / 256;
    prep_kernel<<<prep_blocks, 256, 0, stream>>>(x, Wq, Wk1, Wk2, Wv1, Wv2,
                                                 w1k, w1v, qbuf, zbuf, outacc,
                                                 Bpk, N);

    int edge_blocks = (E + 63) / 64;
    edge_kernel<<<edge_blocks, 256, 0, stream>>>(pos, x, esrc, edst,
                                                 w1k, w1v, qbuf, Bpk,
                                                 zbuf, outacc, E);

    finalize_kernel<<<(N * 8 + 255) / 256, 256, 0, stream>>>(
        outacc, zbuf, d_out, x, N * 8);
}

// Round 11
// 114.562 us; speedup vs baseline: 1.0544x; 1.0544x over previous
//
#include <hip/hip_runtime.h>
#include <hip/hip_bf16.h>

#define NBASIS 10
#define CDIM 16
#define DKDIM 8
#define JDIM 16

typedef _Float16 half8 __attribute__((ext_vector_type(8)));
typedef float floatx4 __attribute__((ext_vector_type(4)));

// adaptive load: f32 flag (wave-uniform) selects fp32 or bf16 interpretation
__device__ __forceinline__ float ldf(const void* p, int i, int f32) {
    if (f32) return ((const float*)p)[i];
    return __bfloat162float(((const __hip_bfloat16*)p)[i]);
}

// per-wave input-dtype detect (round-2 notes): fp32 data read as bf16 shows
// implausible magnitudes in ~half the ushorts; bf16 N(0,1) shows none.
__device__ __forceinline__ int detect_f32(const void* x) {
    unsigned short b = ((const unsigned short*)x)[threadIdx.x & 63];
    float v = __uint_as_float(((unsigned int)b) << 16);
    bool bad = !(fabsf(v) < 1000.0f) || (v != 0.0f && fabsf(v) < 1e-15f);
    unsigned long long m = __ballot(bad);
    return (__popcll(m) >= 8) ? 1 : 0;
}

__device__ __forceinline__ const float* uniform_ptr(const float* p) {
    uint64_t v = (uint64_t)p;
    uint32_t lo = __builtin_amdgcn_readfirstlane((uint32_t)v);
    uint32_t hi = __builtin_amdgcn_readfirstlane((uint32_t)(v >> 32));
    return (const float*)(((uint64_t)hi << 32) | lo);
}

// ---------------- prep (SLIM): W1 fp32, Wq fp32, Bpk fragment-pack ----------
// Bpk flat index = ((nt*8 + ks)*64 + lane)*8 + j  (one dwordx4 per lane/frag)
//   kk = ks*32 + (lane>>4)*8 + j  -> c = kk>>4, jj = kk&15   (K = (c,j) = 256)
//   nn = nt*16 + (lane&15)        -> net = nn>>7, m = (nn>>3)&15, o = nn&7
__global__ __launch_bounds__(256) void prep_kernel(
    const void* __restrict__ x, const void* __restrict__ Wq,
    const void* __restrict__ Wk1, const void* __restrict__ Wk2,
    const void* __restrict__ Wv1, const void* __restrict__ Wv2,
    float* __restrict__ w1k, float* __restrict__ w1v,
    float* __restrict__ wqf, _Float16* __restrict__ Bpk)
{
    const int f32 = detect_f32(x);
    int i = blockIdx.x * 256 + threadIdx.x;
    if (i < 160) { w1k[i] = ldf(Wk1, i, f32); w1v[i] = ldf(Wv1, i, f32); }
    if (i < 128) wqf[i] = ldf(Wq, i, f32);
    if (i < 65536) {
        int j = i & 7, lane = (i >> 3) & 63, ks = (i >> 9) & 7, nt = i >> 12;
        int kk = ks * 32 + (lane >> 4) * 8 + j;
        int nn = nt * 16 + (lane & 15);
        int c = kk >> 4, jj = kk & 15;
        int net = nn >> 7, m = (nn >> 3) & 15, o = nn & 7;
        float v = ldf(net ? Wv2 : Wk2, m * 2048 + c * 128 + jj * 8 + o, f32);
        Bpk[i] = (_Float16)v;
    }
}

// ---------------- edge kernel: geometry -> MFMA GEMM -> in-register epilogue
// block = 256 thr = 4 waves = 64 edges. ks-OUTER GEMM with B software
// pipeline (ks=0 issued before the A barrier, ks+1 prefetched in-loop).
// h-contraction per lane (m = (2nt + col>>3)&15, o = col&7), shfl_xor(8)
// merges m-halves. q = x[d]@Wq computed on the fly in the softmax phase.
__global__ __launch_bounds__(256) void edge_kernel(
    const void* __restrict__ pos, const void* __restrict__ x,
    const int* __restrict__ esrc, const int* __restrict__ edst,
    const float* __restrict__ w1k, const float* __restrict__ w1v,
    const float* __restrict__ wqf, const _Float16* __restrict__ Bpk,
    float* __restrict__ zbuf, float* __restrict__ outacc, int E)
{
    __shared__ _Float16 A[16384];        // [rt][ks][lane][8] fp16 frags, 32 KB
    __shared__ union {
        struct { float xs[64][17]; float sh[64][17]; } g;     // geometry
        struct { float pk[2][64][9]; float pv[2][64][9]; } p; // partial k/v
    } u;
    __shared__ float hmf[2][16][68];     // [net][m][e], conflict-free stride
    __shared__ float wq_lds[128];
    __shared__ float cut_lds[64];
    __shared__ float evs_lds[64];
    __shared__ int   d_lds[64];

    const int f32  = detect_f32(x);
    const int tid  = threadIdx.x;
    const int lane = tid & 63;
    const int w    = tid >> 6;
    const int q    = lane >> 4;
    const int e0   = blockIdx.x * 64;
    const int e_g  = e0 + lane;
    const int eidx = (e_g < E) ? e_g : (E - 1);
    const int s = esrc[eidx], d = edst[eidx];

    if (tid < 128) wq_lds[tid] = wqf[tid];

    // ---- geometry (per-edge work split across the 4 waves) ----
    float vx = ldf(pos, s * 3 + 0, f32) - ldf(pos, d * 3 + 0, f32);
    float vy = ldf(pos, s * 3 + 1, f32) - ldf(pos, d * 3 + 1, f32);
    float vz = ldf(pos, s * 3 + 2, f32) - ldf(pos, d * 3 + 2, f32);
    float r2 = vx * vx + vy * vy + vz * vz;
    float r  = sqrtf(r2 + 1e-18f);          // ref: emb/cutoff radius has +eps

    if (w == 0) {            // spherical harmonics + cutoff + dst
        float rsh = sqrtf(r2);              // ref: SH radius has no eps
        float inv = 1.0f / fmaxf(rsh, 1e-9f);
        float ux = vx * inv, uy = vy * inv, uz = vz * inv;
        const float s3   = 1.7320508075688772f;
        const float s5   = 2.23606797749979f;
        const float s15  = 3.872983346207417f;
        const float c358 = 2.091650066335189f;
        const float c218 = 1.6201851746019651f;
        const float s105 = 10.246950765959598f;
        const float s7h  = 1.3228756555322954f;
        float xx = ux * ux, yy = uy * uy, zz = uz * uz;
        float sh[16];
        sh[0] = 1.0f;
        sh[1] = s3 * ux; sh[2] = s3 * uy; sh[3] = s3 * uz;
        sh[4] = s15 * ux * uy;
        sh[5] = s15 * uy * uz;
        sh[6] = 0.5f * s5 * (3.0f * zz - 1.0f);
        sh[7] = s15 * ux * uz;
        sh[8] = 0.5f * s15 * (xx - yy);
        sh[9] = c358 * uy * (3.0f * xx - yy);
        sh[10] = s105 * ux * uy * uz;
        sh[11] = c218 * uy * (5.0f * zz - 1.0f);
        sh[12] = s7h * uz * (5.0f * zz - 3.0f);
        sh[13] = c218 * ux * (5.0f * zz - 1.0f);
        sh[14] = 0.5f * s105 * uz * (xx - yy);
        sh[15] = c358 * ux * (xx - 3.0f * yy);
        #pragma unroll
        for (int j = 0; j < 16; ++j) u.g.sh[lane][j] = sh[j];
        float tcut = 10.0f * (1.0f - r * (1.0f / 3.5f));
        cut_lds[lane] = (tcut > 0.0f) ? expf(-1.0f / tcut) : 0.0f;
        d_lds[lane] = d;
    } else if (w == 1) {     // xs gather
        #pragma unroll
        for (int c = 0; c < CDIM; ++c)
            u.g.xs[lane][c] = ldf(x, s * CDIM + c, f32);
    } else {                 // w=2: h_k, w=3: h_v -> hmf[net][m][e] (fp32)
        const float* w1 = uniform_ptr((w == 2) ? w1k : w1v);
        const int net = w - 2;
        float emb[NBASIS];
        const float step = 3.5f / 11.0f;
        const float istep = 11.0f / 3.5f;
        const float coef = (float)(1.14136 * 7.38905609893065 * 3.1622776601683795);
        #pragma unroll
        for (int i = 0; i < NBASIS; ++i) {
            float uu = (r - step * (float)(i + 1)) * istep; uu *= uu;
            emb[i] = (uu < 1.0f) ? coef * expf(-1.0f / (1.0f - uu)) : 0.0f;
        }
        const float inv_s10 = 0.31622776601683794f;
        #pragma unroll
        for (int m = 0; m < 16; ++m) {
            float pre = 0.0f;
            #pragma unroll
            for (int nb = 0; nb < NBASIS; ++nb)
                pre = fmaf(emb[nb], w1[nb * 16 + m], pre);
            pre *= inv_s10;
            hmf[net][m][lane] = pre / (1.0f + expf(-pre));   // silu
        }
    }

    // B ks=0 prefetch: independent of LDS -> issues before barriers drain
    const half8* Bf = (const half8*)Bpk;
    half8 bcur[4];
    #pragma unroll
    for (int l = 0; l < 4; ++l)
        bcur[l] = Bf[((4 * w + l) * 8 + 0) * 64 + lane];

    __syncthreads();   // [1] geometry visible

    // ---- A-frag build (wave w -> row-tile rt=w), store to dedicated A ----
    {
        const int erow = w * 16 + (lane & 15);
        const int coff = q >> 1, jj0 = (q & 1) * 8;
        half8* Af = (half8*)A;
        #pragma unroll
        for (int ks = 0; ks < 8; ++ks) {
            float xsv = u.g.xs[erow][ks * 2 + coff];
            half8 a;
            #pragma unroll
            for (int j = 0; j < 8; ++j)
                a[j] = (_Float16)(xsv * u.g.sh[erow][jj0 + j]);
            Af[(w * 8 + ks) * 64 + lane] = a;
        }
    }
    __syncthreads();   // [2] A visible (and all geometry reads complete)

    // ---- GEMM, ks-outer, software-pipelined B ----
    floatx4 acc[4][4];   // [l][rt]
    #pragma unroll
    for (int l = 0; l < 4; ++l)
        #pragma unroll
        for (int rt = 0; rt < 4; ++rt) acc[l][rt] = (floatx4){0.f, 0.f, 0.f, 0.f};
    {
        const half8* Af = (const half8*)A;
        #pragma unroll
        for (int ks = 0; ks < 8; ++ks) {
            half8 bnxt[4];
            if (ks < 7) {
                #pragma unroll
                for (int l = 0; l < 4; ++l)
                    bnxt[l] = Bf[((4 * w + l) * 8 + ks + 1) * 64 + lane];
            }
            half8 a[4];
            #pragma unroll
            for (int rt = 0; rt < 4; ++rt)
                a[rt] = Af[(rt * 8 + ks) * 64 + lane];
            #pragma unroll
            for (int l = 0; l < 4; ++l)
                #pragma unroll
                for (int rt = 0; rt < 4; ++rt)
                    acc[l][rt] = __builtin_amdgcn_mfma_f32_16x16x32_f16(
                        a[rt], bcur[l], acc[l][rt], 0, 0, 0);
            #pragma unroll
            for (int l = 0; l < 4; ++l) bcur[l] = bnxt[l];
        }
    }

    // ---- h-contraction (m = (2nt + b3)&15) + m-half merge ----
    float part[16];      // [rt*4+rr]: partial k or v for edge rt*16+q*4+rr
    #pragma unroll
    for (int i = 0; i < 16; ++i) part[i] = 0.0f;
    const int b3  = (lane >> 3) & 1;
    const int net = w >> 1;             // 0 = k (nt 0-7), 1 = v (nt 8-15)
    #pragma unroll
    for (int l = 0; l < 4; ++l) {
        const int m = (2 * (4 * w + l) + b3) & 15;
        #pragma unroll
        for (int rt = 0; rt < 4; ++rt) {
            const float* hp = &hmf[net][m][rt * 16 + q * 4];
            #pragma unroll
            for (int rr = 0; rr < 4; ++rr)
                part[rt * 4 + rr] = fmaf(hp[rr], acc[l][rt][rr], part[rt * 4 + rr]);
        }
    }
    #pragma unroll
    for (int i = 0; i < 16; ++i) part[i] += __shfl_xor(part[i], 8, 64);

    // partial writes overlay geometry — all g reads finished before [2]
    if (b3 == 0) {
        const int o = lane & 7;
        #pragma unroll
        for (int i = 0; i < 16; ++i) {
            const int e = (i >> 2) * 16 + q * 4 + (i & 3);
            if (w < 2) u.p.pk[w][e][o] = part[i];
            else       u.p.pv[w - 2][e][o] = part[i];
        }
    }
    __syncthreads();   // [3] partials visible

    // ---- softmax: q on-the-fly, logit -> ev -> atomic z (one wave) ----
    if (tid < 64) {
        const int dd = d_lds[tid];
        float xd[CDIM];
        #pragma unroll
        for (int c = 0; c < CDIM; ++c) xd[c] = ldf(x, dd * CDIM + c, f32);
        float logit = 0.0f;
        #pragma unroll
        for (int o = 0; o < 8; ++o) {
            float kv = u.p.pk[0][tid][o] + u.p.pk[1][tid][o];
            float qo = 0.0f;
            #pragma unroll
            for (int c = 0; c < CDIM; ++c)
                qo = fmaf(xd[c], wq_lds[c * 8 + o], qo);
            logit = fmaf(qo, kv, logit);
        }
        // scale: 1/64 (fcnet+norm) * 1/sqrt(8) (dk)
        logit *= (1.0f / 64.0f) * 0.35355339059327373f;
        float ev = cut_lds[tid] * expf(logit);   // unstabilized, matches ref
        if (e0 + tid < E) atomicAdd(&zbuf[dd], ev);
        evs_lds[tid] = sqrtf(ev);
    }
    __syncthreads();   // [4] ev visible

    // ---- out += sqrt(ev) * v (folded softmax; finalize divides by sqrt(z))
    {
        const int el = tid & 63, op = tid >> 6;
        if (e0 + el < E) {
            const int dd = d_lds[el];
            const float wq = evs_lds[el] * (1.0f / 64.0f);
            float v0 = u.p.pv[0][el][2 * op]     + u.p.pv[1][el][2 * op];
            float v1 = u.p.pv[0][el][2 * op + 1] + u.p.pv[1][el][2 * op + 1];
            atomicAdd(&outacc[(size_t)dd * 8 + 2 * op],     wq * v0);
            atomicAdd(&outacc[(size_t)dd * 8 + 2 * op + 1], wq * v1);
        }
    }
}

// ---------------- finalize: out = outacc / sqrt(z), dtype-adaptive ----------
__global__ __launch_bounds__(256) void finalize_kernel(
    const float* __restrict__ outacc, const float* __restrict__ zbuf,
    void* __restrict__ out, const void* __restrict__ x, int n)
{
    const int f32 = detect_f32(x);
    int i = blockIdx.x * 256 + threadIdx.x;
    if (i < n) {
        float z = zbuf[i >> 3];
        z = (z == 0.0f) ? 1.0f : z;
        float val = outacc[i] / sqrtf(z);
        if (f32) ((float*)out)[i] = val;
        else ((__hip_bfloat16*)out)[i] = __float2bfloat16(val);
    }
}

extern "C" void kernel_launch(void* const* d_in, const int* in_sizes, int n_in,
                              void* d_out, int out_size, void* d_ws, size_t ws_size,
                              hipStream_t stream)
{
    const void* pos = d_in[0];
    const void* x   = d_in[1];
    const void* Wq  = d_in[2];
    const void* Wk1 = d_in[3];
    const void* Wk2 = d_in[4];
    const void* Wv1 = d_in[5];
    const void* Wv2 = d_in[6];
    const int* esrc = (const int*)d_in[7];
    const int* edst = (const int*)d_in[8];
    const int N = in_sizes[1] / CDIM;
    const int E = in_sizes[7];

    float* ws = (float*)d_ws;
    float* w1k    = ws;                          // 160
    float* w1v    = w1k + 160;                   // 160
    float* wqf    = w1v + 160;                   // 128
    float* zbuf   = wqf + 128;                   // N      (zbuf+outacc
    float* outacc = zbuf + N;                    // N*8     contiguous)
    _Float16* Bpk = (_Float16*)(outacc + (size_t)N * 8);  // 65536 fp16

    // zero z + out accumulators in one async memset (graph-capturable node)
    hipMemsetAsync(zbuf, 0, (size_t)N * 9 * sizeof(float), stream);

    prep_kernel<<<256, 256, 0, stream>>>(x, Wq, Wk1, Wk2, Wv1, Wv2,
                                         w1k, w1v, wqf, Bpk);

    int edge_blocks = (E + 63) / 64;
    edge_kernel<<<edge_blocks, 256, 0, stream>>>(pos, x, esrc, edst,
                                                 w1k, w1v, wqf, Bpk,
                                                 zbuf, outacc, E);

    finalize_kernel<<<(N * 8 + 255) / 256, 256, 0, stream>>>(
        outacc, zbuf, d_out, x, N * 8);
}